// Round 1
// baseline (6949.935 us; speedup 1.0000x reference)
//
#include <hip/hip_runtime.h>
#include <math.h>

// Model dims (fixed by the reference)
#define DMODEL 768
#define SEQL   512
#define NBATCH 8
#define NHEAD  12
#define NLAYER 6
#define FFDIM  3072
#define DHEAD  64
#define ROWS   (NBATCH * SEQL)        // 4096
#define ATTN_PER_LAYER ((size_t)NBATCH * NHEAD * SEQL * SEQL)  // 25,165,824

// ---------------------------------------------------------------------------
// Embedding + (faithful buggy) positional encoding: h[b,l,:] = emb[x[b,l],:] + pe[b,:]
__global__ __launch_bounds__(256) void embed_kernel(const int* __restrict__ x,
                                                    const float* __restrict__ emb,
                                                    float* __restrict__ h) {
    int bl = blockIdx.x;            // 0..4095 = b*512 + l
    int b = bl >> 9;
    int tok = x[bl];
    const float* e = emb + (size_t)tok * DMODEL;
    float* hp = h + (size_t)bl * DMODEL;
    const float c = -0.011992632f;  // -log(10000)/768
#pragma unroll
    for (int u = 0; u < 3; ++u) {
        int d = threadIdx.x + u * 256;
        int i = d >> 1;
        float div = expf((float)(2 * i) * c);
        float ang = (float)b * div;
        float pe = (d & 1) ? cosf(ang) : sinf(ang);
        hp[d] = e[d] + pe;
    }
}

// ---------------------------------------------------------------------------
// LayerNorm: one block per row of 768
__global__ __launch_bounds__(256) void ln_kernel(const float* __restrict__ X,
                                                 const float* __restrict__ g,
                                                 const float* __restrict__ be,
                                                 float* __restrict__ Y) {
    int row = blockIdx.x;
    const float* x = X + (size_t)row * DMODEL;
    float* y = Y + (size_t)row * DMODEL;
    int t = threadIdx.x;
    float v0 = x[t], v1 = x[t + 256], v2 = x[t + 512];
    float s = v0 + v1 + v2;
    __shared__ float sb[8];
    for (int off = 32; off; off >>= 1) s += __shfl_down(s, off, 64);
    int lane = t & 63, wid = t >> 6;
    if (!lane) sb[wid] = s;
    __syncthreads();
    float mean = (sb[0] + sb[1] + sb[2] + sb[3]) * (1.0f / DMODEL);
    float d0 = v0 - mean, d1 = v1 - mean, d2 = v2 - mean;
    float q = d0 * d0 + d1 * d1 + d2 * d2;
    for (int off = 32; off; off >>= 1) q += __shfl_down(q, off, 64);
    if (!lane) sb[4 + wid] = q;
    __syncthreads();
    float var = (sb[4] + sb[5] + sb[6] + sb[7]) * (1.0f / DMODEL);
    float inv = 1.0f / sqrtf(var + 1e-5f);
    y[t]       = d0 * inv * g[t]       + be[t];
    y[t + 256] = d1 * inv * g[t + 256] + be[t + 256];
    y[t + 512] = d2 * inv * g[t + 512] + be[t + 512];
}

// ---------------------------------------------------------------------------
// Generic tiled fp32 GEMM: C[m,n] (+)= A[m,:] @ W[:,n] + bias[n], optional GELU.
// Batched via blockIdx.z decomposed as zb = z / zmod, zh = z % zmod with
// per-operand strides. flags: 1 = exact GELU, 2 = residual accumulate into C.
__global__ __launch_bounds__(256) void gemm_kernel(
    const float* __restrict__ A, const float* __restrict__ W,
    const float* __restrict__ bias, float* __restrict__ C,
    int M, int N, int K, int lda, int ldw, int ldc,
    int zmod, long long sAb, long long sAh, long long sWb, long long sWh,
    long long sCb, long long sCh, int flags) {
    int z = blockIdx.z;
    int zb = z / zmod, zh = z % zmod;
    A += zb * sAb + zh * sAh;
    W += zb * sWb + zh * sWh;
    C += zb * sCb + zh * sCh;

    __shared__ float As[16][65];
    __shared__ float Bs[16][64];
    int m0 = blockIdx.y * 64, n0 = blockIdx.x * 64;
    int tid = threadIdx.x;
    int tx = tid & 15, ty = tid >> 4;
    int arow = tid >> 2;            // 0..63
    int akk  = (tid & 3) << 2;      // 0,4,8,12
    int bkk  = tid >> 4;            // 0..15
    int bnn  = (tid & 15) << 2;     // 0..60
    float acc[4][4] = {};

    for (int k0 = 0; k0 < K; k0 += 16) {
        float4 av = *(const float4*)(A + (size_t)(m0 + arow) * lda + k0 + akk);
        float4 wv = *(const float4*)(W + (size_t)(k0 + bkk) * ldw + n0 + bnn);
        As[akk + 0][arow] = av.x;
        As[akk + 1][arow] = av.y;
        As[akk + 2][arow] = av.z;
        As[akk + 3][arow] = av.w;
        *(float4*)&Bs[bkk][bnn] = wv;
        __syncthreads();
#pragma unroll
        for (int k = 0; k < 16; ++k) {
            float a[4], bb[4];
#pragma unroll
            for (int i = 0; i < 4; ++i) a[i] = As[k][ty * 4 + i];
#pragma unroll
            for (int j = 0; j < 4; ++j) bb[j] = Bs[k][tx * 4 + j];
#pragma unroll
            for (int i = 0; i < 4; ++i)
#pragma unroll
                for (int j = 0; j < 4; ++j) acc[i][j] = fmaf(a[i], bb[j], acc[i][j]);
        }
        __syncthreads();
    }

#pragma unroll
    for (int i = 0; i < 4; ++i) {
        size_t rbase = (size_t)(m0 + ty * 4 + i) * ldc;
#pragma unroll
        for (int j = 0; j < 4; ++j) {
            int col = n0 + tx * 4 + j;
            float v = acc[i][j] + (bias ? bias[col] : 0.0f);
            if (flags & 1) v = 0.5f * v * (1.0f + erff(v * 0.70710678118654752f));
            if (flags & 2) C[rbase + col] += v;
            else           C[rbase + col] = v;
        }
    }
}

// ---------------------------------------------------------------------------
// Attention scores: P[b,h,q,k] = (Q[b,q,h,:]·K[b,k,h,:])/8 - 0.01*(q-k), mask.
// Block = 64 q rows x 32 k cols. Grid: (L/32, L/64, B*H).
__global__ __launch_bounds__(256) void scores_kernel(const float* __restrict__ Q,
                                                     const float* __restrict__ Kmat,
                                                     const int* __restrict__ mask,
                                                     float* __restrict__ P) {
    int kt = blockIdx.x, qt = blockIdx.y, bh = blockIdx.z;
    int b = bh / NHEAD, hh = bh % NHEAD;
    int q0 = qt * 64, k0 = kt * 32;
    __shared__ float Qs[64][65];
    __shared__ float Ks[32][65];
    const float* Qg = Q + ((size_t)(b * SEQL + q0)) * DMODEL + hh * DHEAD;
    const float* Kg = Kmat + ((size_t)(b * SEQL + k0)) * DMODEL + hh * DHEAD;
    {
        int r = threadIdx.x >> 2;
        int c0 = (threadIdx.x & 3) * 16;
#pragma unroll
        for (int u = 0; u < 4; ++u) {
            float4 v = *(const float4*)(Qg + (size_t)r * DMODEL + c0 + u * 4);
            Qs[r][c0 + u * 4 + 0] = v.x;
            Qs[r][c0 + u * 4 + 1] = v.y;
            Qs[r][c0 + u * 4 + 2] = v.z;
            Qs[r][c0 + u * 4 + 3] = v.w;
        }
    }
    {
        int r = threadIdx.x >> 3;
        int c0 = (threadIdx.x & 7) * 8;
#pragma unroll
        for (int u = 0; u < 2; ++u) {
            float4 v = *(const float4*)(Kg + (size_t)r * DMODEL + c0 + u * 4);
            Ks[r][c0 + u * 4 + 0] = v.x;
            Ks[r][c0 + u * 4 + 1] = v.y;
            Ks[r][c0 + u * 4 + 2] = v.z;
            Ks[r][c0 + u * 4 + 3] = v.w;
        }
    }
    __syncthreads();
    int tq = threadIdx.x >> 3;      // 0..31 -> q pair
    int tk = threadIdx.x & 7;       // 0..7  -> 4 k each
    float acc[2][4] = {};
#pragma unroll 8
    for (int d = 0; d < 64; ++d) {
        float qa0 = Qs[tq * 2 + 0][d];
        float qa1 = Qs[tq * 2 + 1][d];
#pragma unroll
        for (int j = 0; j < 4; ++j) {
            float kb = Ks[tk * 4 + j][d];
            acc[0][j] = fmaf(qa0, kb, acc[0][j]);
            acc[1][j] = fmaf(qa1, kb, acc[1][j]);
        }
    }
    size_t pbase = ((size_t)(b * NHEAD + hh)) * SEQL;
#pragma unroll
    for (int i = 0; i < 2; ++i) {
        int qg = q0 + tq * 2 + i;
#pragma unroll
        for (int j = 0; j < 4; ++j) {
            int kg = k0 + tk * 4 + j;
            float v = acc[i][j] * 0.125f - 0.01f * ((float)qg - (float)kg);
            if (mask[b * SEQL + kg] == 0) v = -INFINITY;
            P[(pbase + qg) * SEQL + kg] = v;
        }
    }
}

// ---------------------------------------------------------------------------
// In-place softmax over rows of length 512. One wave per row, 4 rows/block.
__global__ __launch_bounds__(256) void softmax_kernel(float* __restrict__ P) {
    int row = blockIdx.x * 4 + (threadIdx.x >> 6);
    int lane = threadIdx.x & 63;
    float* p = P + (size_t)row * SEQL;
    float v[8];
#pragma unroll
    for (int j = 0; j < 8; ++j) v[j] = p[lane + 64 * j];
    float m = v[0];
#pragma unroll
    for (int j = 1; j < 8; ++j) m = fmaxf(m, v[j]);
    for (int off = 32; off; off >>= 1) m = fmaxf(m, __shfl_xor(m, off, 64));
    float s = 0.0f;
#pragma unroll
    for (int j = 0; j < 8; ++j) {
        v[j] = expf(v[j] - m);
        s += v[j];
    }
    for (int off = 32; off; off >>= 1) s += __shfl_xor(s, off, 64);
    float inv = 1.0f / s;
#pragma unroll
    for (int j = 0; j < 8; ++j) p[lane + 64 * j] = v[j] * inv;
}

// ---------------------------------------------------------------------------
// Final logits: out[b] = h[b,0,:]·Wc + bc. Grid = 8 blocks.
__global__ __launch_bounds__(256) void logits_kernel(const float* __restrict__ h,
                                                     const float* __restrict__ Wc,
                                                     const float* __restrict__ bc,
                                                     float* __restrict__ out) {
    int b = blockIdx.x;
    const float* hp = h + (size_t)b * SEQL * DMODEL;
    int t = threadIdx.x;
    float s = hp[t] * Wc[t] + hp[t + 256] * Wc[t + 256] + hp[t + 512] * Wc[t + 512];
    __shared__ float sb[4];
    for (int off = 32; off; off >>= 1) s += __shfl_down(s, off, 64);
    int lane = t & 63, wid = t >> 6;
    if (!lane) sb[wid] = s;
    __syncthreads();
    if (t == 0) out[b] = sb[0] + sb[1] + sb[2] + sb[3] + bc[0];
}

// ---------------------------------------------------------------------------
extern "C" void kernel_launch(void* const* d_in, const int* in_sizes, int n_in,
                              void* d_out, int out_size, void* d_ws, size_t ws_size,
                              hipStream_t stream) {
    (void)in_sizes; (void)n_in; (void)out_size; (void)ws_size;
    const int*   x    = (const int*)d_in[0];
    const int*   mask = (const int*)d_in[1];
    const float* emb  = (const float*)d_in[2];
    const float* Wq   = (const float*)d_in[3];
    const float* bq   = (const float*)d_in[4];
    const float* Wk   = (const float*)d_in[5];
    const float* bk   = (const float*)d_in[6];
    const float* Wv   = (const float*)d_in[7];
    const float* bv   = (const float*)d_in[8];
    const float* Wo   = (const float*)d_in[9];
    const float* bo   = (const float*)d_in[10];
    const float* W1   = (const float*)d_in[11];
    const float* b1   = (const float*)d_in[12];
    const float* W2   = (const float*)d_in[13];
    const float* b2   = (const float*)d_in[14];
    const float* g1   = (const float*)d_in[15];
    const float* be1  = (const float*)d_in[16];
    const float* g2   = (const float*)d_in[17];
    const float* be2  = (const float*)d_in[18];
    const float* Wc   = (const float*)d_in[19];
    const float* bc   = (const float*)d_in[20];

    float* out  = (float*)d_out;
    float* attn = out + NBATCH * 1;   // logits first (8 floats), then attn_all

    const size_t RD = (size_t)ROWS * DMODEL;     // 3,145,728
    float* ws = (float*)d_ws;
    float* h   = ws;
    float* xn  = h + RD;
    float* Qb  = xn + RD;
    float* Kb  = Qb + RD;
    float* Vb  = Kb + RD;
    float* att = Vb + RD;
    float* ff  = att + RD;                       // ROWS*FFDIM

    embed_kernel<<<ROWS, 256, 0, stream>>>(x, emb, h);

    for (int l = 0; l < NLAYER; ++l) {
        const float* wq = Wq + (size_t)l * DMODEL * DMODEL;
        const float* wk = Wk + (size_t)l * DMODEL * DMODEL;
        const float* wv = Wv + (size_t)l * DMODEL * DMODEL;
        const float* wo = Wo + (size_t)l * DMODEL * DMODEL;
        const float* w1 = W1 + (size_t)l * DMODEL * FFDIM;
        const float* w2 = W2 + (size_t)l * FFDIM * DMODEL;
        float* P = attn + (size_t)l * ATTN_PER_LAYER;

        ln_kernel<<<ROWS, 256, 0, stream>>>(h, g1 + l * DMODEL, be1 + l * DMODEL, xn);

        dim3 gdd(DMODEL / 64, ROWS / 64, 1);
        gemm_kernel<<<gdd, 256, 0, stream>>>(xn, wq, bq + l * DMODEL, Qb,
            ROWS, DMODEL, DMODEL, DMODEL, DMODEL, DMODEL, 1, 0, 0, 0, 0, 0, 0, 0);
        gemm_kernel<<<gdd, 256, 0, stream>>>(xn, wk, bk + l * DMODEL, Kb,
            ROWS, DMODEL, DMODEL, DMODEL, DMODEL, DMODEL, 1, 0, 0, 0, 0, 0, 0, 0);
        gemm_kernel<<<gdd, 256, 0, stream>>>(xn, wv, bv + l * DMODEL, Vb,
            ROWS, DMODEL, DMODEL, DMODEL, DMODEL, DMODEL, 1, 0, 0, 0, 0, 0, 0, 0);

        scores_kernel<<<dim3(SEQL / 32, SEQL / 64, NBATCH * NHEAD), 256, 0, stream>>>(
            Qb, Kb, mask, P);
        softmax_kernel<<<(NBATCH * NHEAD * SEQL) / 4, 256, 0, stream>>>(P);

        // PV: per (b,h) [512x512] @ [512x64] -> att[b,q,h,:]
        gemm_kernel<<<dim3(1, SEQL / 64, NBATCH * NHEAD), 256, 0, stream>>>(
            P, Vb, nullptr, att,
            SEQL, DHEAD, SEQL, SEQL, DMODEL, DMODEL,
            NHEAD,
            (long long)NHEAD * SEQL * SEQL, (long long)SEQL * SEQL,
            (long long)SEQL * DMODEL, (long long)DHEAD,
            (long long)SEQL * DMODEL, (long long)DHEAD, 0);

        // h += att @ Wo + bo
        gemm_kernel<<<gdd, 256, 0, stream>>>(att, wo, bo + l * DMODEL, h,
            ROWS, DMODEL, DMODEL, DMODEL, DMODEL, DMODEL, 1, 0, 0, 0, 0, 0, 0, 2);

        ln_kernel<<<ROWS, 256, 0, stream>>>(h, g2 + l * DMODEL, be2 + l * DMODEL, xn);

        // ff = gelu(xn @ W1 + b1)
        gemm_kernel<<<dim3(FFDIM / 64, ROWS / 64, 1), 256, 0, stream>>>(
            xn, w1, b1 + l * FFDIM, ff,
            ROWS, FFDIM, DMODEL, DMODEL, FFDIM, FFDIM, 1, 0, 0, 0, 0, 0, 0, 1);

        // h += ff @ W2 + b2
        gemm_kernel<<<gdd, 256, 0, stream>>>(ff, w2, b2 + l * DMODEL, h,
            ROWS, DMODEL, FFDIM, FFDIM, DMODEL, DMODEL, 1, 0, 0, 0, 0, 0, 0, 2);
    }

    logits_kernel<<<NBATCH, 256, 0, stream>>>(h, Wc, bc, out);
}